// Round 1
// baseline (26.118 us; speedup 1.0000x reference)
//
#include <hip/hip_runtime.h>
#include <math.h>

// Problem: SEQ=20, BATCH=131072, IN=1, HID=50.
// Reference epilogue slices out[:, -1:, :] on the BATCH axis, so the output
// (20 floats) depends ONLY on batch row 131071. Everything else is dead code.
// => run the 20-step LSTM recurrence for a single batch row in one workgroup.

constexpr int SEQ   = 20;
constexpr int BATCH = 131072;
constexpr int HID   = 50;
constexpr int NG    = 4 * HID;   // 200 gates

__global__ __launch_bounds__(256)
void lstm_last_row_kernel(const float* __restrict__ x,      // (SEQ, BATCH, 1)
                          const float* __restrict__ w_ih,   // (200, 1)
                          const float* __restrict__ w_hh,   // (200, 50)
                          const float* __restrict__ b_ih,   // (200,)
                          const float* __restrict__ b_hh,   // (200,)
                          const float* __restrict__ w_fc,   // (1, 50)
                          const float* __restrict__ b_fc,   // (1,)
                          float* __restrict__ out)          // (SEQ, 1, 1) = 20
{
    __shared__ float s_whh[NG * HID];   // 40 KB: w_hh staged once, reused 20x
    __shared__ float s_h[HID];          // hidden state (broadcast to 200 gate threads)
    __shared__ float s_gates[NG];
    __shared__ float s_out[HID];

    const int tid = threadIdx.x;

    // Stage w_hh into LDS (row-major, same layout as global).
    for (int i = tid; i < NG * HID; i += 256)
        s_whh[i] = w_hh[i];
    if (tid < HID) s_h[tid] = 0.0f;

    // Per-thread invariants.
    float bias = 0.0f, wih = 0.0f;
    if (tid < NG) {
        bias = b_ih[tid] + b_hh[tid];
        wih  = w_ih[tid];              // IN == 1, so one scalar per gate row
    }
    const float wfc = (tid < HID) ? w_fc[tid] : 0.0f;
    const float bfc = b_fc[0];

    float c = 0.0f;                    // cell state: thread j owns c[j], j<HID
    __syncthreads();

    for (int t = 0; t < SEQ; ++t) {
        // ---- gates[g] = x_t * w_ih[g] + (b_ih+b_hh)[g] + dot(h, w_hh[g,:]) ----
        if (tid < NG) {
            float g = fmaf(x[(size_t)t * BATCH + (BATCH - 1)], wih, bias);
            const float* row = &s_whh[tid * HID];
            #pragma unroll
            for (int k = 0; k < HID; ++k)
                g = fmaf(s_h[k], row[k], g);
            s_gates[tid] = g;
        }
        __syncthreads();   // gates ready; also orders next s_h write after reads

        // ---- i,f,g,o -> c, h (thread j owns hidden unit j) ----
        if (tid < HID) {
            const float ig = 1.0f / (1.0f + expf(-s_gates[tid]));
            const float fg = 1.0f / (1.0f + expf(-s_gates[HID + tid]));
            const float gg = tanhf(s_gates[2 * HID + tid]);
            const float og = 1.0f / (1.0f + expf(-s_gates[3 * HID + tid]));
            c = fg * c + ig * gg;
            const float h = og * tanhf(c);
            s_h[tid]   = h;
            s_out[tid] = h * wfc;      // partial product for the fc epilogue
        }
        __syncthreads();   // h/s_out visible to all

        // ---- out[t] = dot(h_t, w_fc) + b_fc (tiny serial sum, fine) ----
        if (tid == 0) {
            float acc = 0.0f;
            for (int k = 0; k < HID; ++k) acc += s_out[k];
            out[t] = acc + bfc;
        }
        // No barrier needed here: next gate phase writes only s_gates (next
        // s_out/s_h writes are behind the next barrier, which thread 0 also
        // reaches only after finishing this sum).
    }
}

extern "C" void kernel_launch(void* const* d_in, const int* in_sizes, int n_in,
                              void* d_out, int out_size, void* d_ws, size_t ws_size,
                              hipStream_t stream) {
    const float* x    = (const float*)d_in[0];
    const float* w_ih = (const float*)d_in[1];
    const float* w_hh = (const float*)d_in[2];
    const float* b_ih = (const float*)d_in[3];
    const float* b_hh = (const float*)d_in[4];
    const float* w_fc = (const float*)d_in[5];
    const float* b_fc = (const float*)d_in[6];
    float* out = (float*)d_out;

    lstm_last_row_kernel<<<1, 256, 0, stream>>>(x, w_ih, w_hh, b_ih, b_hh,
                                                w_fc, b_fc, out);
}

// Round 2
// 23.864 us; speedup vs baseline: 1.0945x; 1.0945x over previous
//
#include <hip/hip_runtime.h>
#include <math.h>

// SEQ=20, BATCH=131072, IN=1, HID=50. Reference slices out[:, -1:, :] on the
// BATCH axis -> output (20 floats) depends only on batch row 131071.
// Single-wave, barrier-free, fully in-register LSTM recurrence:
//   lane j<50 owns hidden unit j; its 4 w_hh rows live in VGPRs;
//   h is broadcast lane->all via v_readlane; fc epilogue is a shfl butterfly.

constexpr int SEQ   = 20;
constexpr int BATCH = 131072;
constexpr int HID   = 50;

__device__ __forceinline__ float bcast(float v, int srcLane) {
    return __uint_as_float(__builtin_amdgcn_readlane(__float_as_uint(v), srcLane));
}
__device__ __forceinline__ float rcp_fast(float v) {
    return __builtin_amdgcn_rcpf(v);
}
__device__ __forceinline__ float sigmoid_f(float v) {
    // e^-x = inf -> rcp(inf) = 0 (correct); e^-x = 0 -> 1 (correct)
    return rcp_fast(1.0f + __expf(-v));
}
__device__ __forceinline__ float tanh_f(float v) {
    // 1 - 2/(e^{2x}+1): inf -> 1, 0 -> -1; NaN-safe at both limits
    return 1.0f - 2.0f * rcp_fast(__expf(2.0f * v) + 1.0f);
}

__global__ __launch_bounds__(64, 1)
void lstm_last_row_kernel(const float* __restrict__ x,      // (SEQ, BATCH, 1)
                          const float* __restrict__ w_ih,   // (200, 1)
                          const float* __restrict__ w_hh,   // (200, 50)
                          const float* __restrict__ b_ih,   // (200,)
                          const float* __restrict__ b_hh,   // (200,)
                          const float* __restrict__ w_fc,   // (1, 50)
                          const float* __restrict__ b_fc,   // (1,)
                          float* __restrict__ out)          // (SEQ,1,1) = 20
{
    const int lane = threadIdx.x;                 // 0..63, single wave
    const int j    = (lane < HID) ? lane : (HID - 1);  // clamp: keep lanes 50..63 finite

    // ---- load this lane's 4 w_hh rows (i,f,g,o for unit j) into registers ----
    float w[4][HID];
    #pragma unroll
    for (int g = 0; g < 4; ++g) {
        const float* row = w_hh + (size_t)(g * HID + j) * HID;  // row start is even -> 8B aligned
        #pragma unroll
        for (int k = 0; k < HID; k += 2) {
            float2 v = *reinterpret_cast<const float2*>(row + k);
            w[g][k]     = v.x;
            w[g][k + 1] = v.y;
        }
    }
    float bias[4], wih[4];
    #pragma unroll
    for (int g = 0; g < 4; ++g) {
        const int r = g * HID + j;
        bias[g] = b_ih[r] + b_hh[r];
        wih[g]  = w_ih[r];                        // IN == 1
    }
    const float wfc = (lane < HID) ? w_fc[lane] : 0.0f;  // lanes >=50 contribute 0
    const float bfc = b_fc[0];

    // ---- preload all 20 x scalars in parallel (one memory round trip) ----
    float xv = 0.0f;
    if (lane < SEQ) xv = x[(size_t)lane * BATCH + (BATCH - 1)];

    float h = 0.0f, c = 0.0f;

    #pragma unroll
    for (int t = 0; t < SEQ; ++t) {
        const float xt = bcast(xv, t);

        float a0 = fmaf(xt, wih[0], bias[0]);
        float a1 = fmaf(xt, wih[1], bias[1]);
        float a2 = fmaf(xt, wih[2], bias[2]);
        float a3 = fmaf(xt, wih[3], bias[3]);

        #pragma unroll
        for (int k = 0; k < HID; ++k) {
            const float hk = bcast(h, k);         // v_readlane -> SGPR operand
            a0 = fmaf(hk, w[0][k], a0);
            a1 = fmaf(hk, w[1][k], a1);
            a2 = fmaf(hk, w[2][k], a2);
            a3 = fmaf(hk, w[3][k], a3);
        }

        const float ig = sigmoid_f(a0);
        const float fg = sigmoid_f(a1);
        const float gg = tanh_f(a2);
        const float og = sigmoid_f(a3);
        c = fmaf(fg, c, ig * gg);
        h = og * tanh_f(c);

        // ---- out[t] = dot(h, w_fc) + b_fc : 6-step butterfly over the wave ----
        float p = h * wfc;
        #pragma unroll
        for (int off = 32; off > 0; off >>= 1)
            p += __shfl_xor(p, off);
        if (lane == 0) out[t] = p + bfc;
    }
}

extern "C" void kernel_launch(void* const* d_in, const int* in_sizes, int n_in,
                              void* d_out, int out_size, void* d_ws, size_t ws_size,
                              hipStream_t stream) {
    const float* x    = (const float*)d_in[0];
    const float* w_ih = (const float*)d_in[1];
    const float* w_hh = (const float*)d_in[2];
    const float* b_ih = (const float*)d_in[3];
    const float* b_hh = (const float*)d_in[4];
    const float* w_fc = (const float*)d_in[5];
    const float* b_fc = (const float*)d_in[6];
    float* out = (float*)d_out;

    lstm_last_row_kernel<<<1, 64, 0, stream>>>(x, w_ih, w_hh, b_ih, b_hh,
                                               w_fc, b_fc, out);
}

// Round 3
// 18.913 us; speedup vs baseline: 1.3809x; 1.2617x over previous
//
#include <hip/hip_runtime.h>
#include <math.h>

// SEQ=20, BATCH=131072, IN=1, HID=50. Reference slices out[:, -1:, :] on the
// BATCH axis -> output (20 floats) depends only on batch row 131071.
// Single-wave, barrier-free (in main loop), in-register LSTM recurrence.
//  - lane j<50 owns hidden unit j; its 4 w_hh rows live in VGPRs as float2
//  - h broadcast via LDS write + ds_read_b128 (same-wave LDS is in-order,
//    same-address read = broadcast; no barrier, no readlane chain)
//  - matvec shaped for v_pk_fma_f32 SLP (paired .x/.y accumulators)
//  - fc reduction deferred past the loop: 20 independent butterflies pipeline

constexpr int SEQ   = 20;
constexpr int BATCH = 131072;
constexpr int HID   = 50;

__device__ __forceinline__ float bcast(float v, int srcLane) {
    return __uint_as_float(__builtin_amdgcn_readlane(__float_as_uint(v), srcLane));
}
__device__ __forceinline__ float rcp_fast(float v) {
    return __builtin_amdgcn_rcpf(v);
}
__device__ __forceinline__ float sigmoid_f(float v) {
    return rcp_fast(1.0f + __expf(-v));     // limits: +inf->0, 0->1 (exact)
}
__device__ __forceinline__ float tanh_f(float v) {
    return 1.0f - 2.0f * rcp_fast(__expf(2.0f * v) + 1.0f);  // NaN-safe both limits
}

__global__ __launch_bounds__(64, 1)
void lstm_last_row_kernel(const float* __restrict__ x,      // (SEQ, BATCH, 1)
                          const float* __restrict__ w_ih,   // (200, 1)
                          const float* __restrict__ w_hh,   // (200, 50)
                          const float* __restrict__ b_ih,   // (200,)
                          const float* __restrict__ b_hh,   // (200,)
                          const float* __restrict__ w_fc,   // (1, 50)
                          const float* __restrict__ b_fc,   // (1,)
                          float* __restrict__ out)          // (SEQ,1,1) = 20
{
    __shared__ __align__(16) float s_w[4 * HID * HID];  // 40 KB staged w_hh
    __shared__ __align__(16) float s_h[52];             // h + zero pad to 13*float4

    const int lane = threadIdx.x;                       // single wave
    const int j    = (lane < HID) ? lane : (HID - 1);   // clamp idle lanes

    // ---- coalesced stage of w_hh (2500 float4) into LDS ----
    const float4* wsrc = reinterpret_cast<const float4*>(w_hh);
    float4*       wdst = reinterpret_cast<float4*>(s_w);
    #pragma unroll
    for (int i = 0; i < 39; ++i)
        wdst[lane + i * 64] = wsrc[lane + i * 64];
    if (lane < 2500 - 39 * 64)                          // tail: 4 float4
        wdst[lane + 39 * 64] = wsrc[lane + 39 * 64];
    if (lane < 52) s_h[lane] = 0.0f;                    // h0 = 0 (+ zero pad)
    __syncthreads();

    // ---- per-lane weight rows (i,f,g,o for unit j) as float2 pairs ----
    float2 w2[4][26];                                   // 26th pair = 0 (pad)
    #pragma unroll
    for (int g = 0; g < 4; ++g) {
        const float* row = &s_w[(g * HID + j) * HID];   // 8B-aligned (200B rows)
        #pragma unroll
        for (int k = 0; k < 25; ++k)
            w2[g][k] = *reinterpret_cast<const float2*>(row + 2 * k);
        w2[g][25] = make_float2(0.0f, 0.0f);
    }

    float bias[4], wih[4];
    #pragma unroll
    for (int g = 0; g < 4; ++g) {
        const int r = g * HID + j;
        bias[g] = b_ih[r] + b_hh[r];
        wih[g]  = w_ih[r];                              // IN == 1
    }
    const float wfc = (lane < HID) ? w_fc[lane] : 0.0f;
    const float bfc = b_fc[0];

    // ---- preload all 20 x scalars in parallel ----
    float xv = 0.0f;
    if (lane < SEQ) xv = x[(size_t)lane * BATCH + (BATCH - 1)];

    float h = 0.0f, c = 0.0f;
    float h_hist[SEQ];

    #pragma unroll
    for (int t = 0; t < SEQ; ++t) {
        // publish h_{t-1}: same-wave LDS is processed in order -> no barrier.
        // (t=0 uses the zeros written before __syncthreads above)
        if (t > 0 && lane < HID) s_h[lane] = h;

        const float xt = bcast(xv, t);
        float2 a0 = make_float2(fmaf(xt, wih[0], bias[0]), 0.0f);
        float2 a1 = make_float2(fmaf(xt, wih[1], bias[1]), 0.0f);
        float2 a2 = make_float2(fmaf(xt, wih[2], bias[2]), 0.0f);
        float2 a3 = make_float2(fmaf(xt, wih[3], bias[3]), 0.0f);

        #pragma unroll
        for (int i = 0; i < 13; ++i) {
            const float4 hv = *reinterpret_cast<const float4*>(&s_h[i * 4]);
            // paired .x/.y updates with adjacent operands -> v_pk_fma_f32 SLP
            a0.x = fmaf(hv.x, w2[0][2*i].x,   a0.x);
            a0.y = fmaf(hv.y, w2[0][2*i].y,   a0.y);
            a1.x = fmaf(hv.x, w2[1][2*i].x,   a1.x);
            a1.y = fmaf(hv.y, w2[1][2*i].y,   a1.y);
            a2.x = fmaf(hv.x, w2[2][2*i].x,   a2.x);
            a2.y = fmaf(hv.y, w2[2][2*i].y,   a2.y);
            a3.x = fmaf(hv.x, w2[3][2*i].x,   a3.x);
            a3.y = fmaf(hv.y, w2[3][2*i].y,   a3.y);
            a0.x = fmaf(hv.z, w2[0][2*i+1].x, a0.x);
            a0.y = fmaf(hv.w, w2[0][2*i+1].y, a0.y);
            a1.x = fmaf(hv.z, w2[1][2*i+1].x, a1.x);
            a1.y = fmaf(hv.w, w2[1][2*i+1].y, a1.y);
            a2.x = fmaf(hv.z, w2[2][2*i+1].x, a2.x);
            a2.y = fmaf(hv.w, w2[2][2*i+1].y, a2.y);
            a3.x = fmaf(hv.z, w2[3][2*i+1].x, a3.x);
            a3.y = fmaf(hv.w, w2[3][2*i+1].y, a3.y);
        }

        const float ig = sigmoid_f(a0.x + a0.y);
        const float fg = sigmoid_f(a1.x + a1.y);
        const float gg = tanh_f(a2.x + a2.y);
        const float og = sigmoid_f(a3.x + a3.y);
        c = fmaf(fg, c, ig * gg);
        h = og * tanh_f(c);
        h_hist[t] = h;
    }

    // ---- deferred fc epilogue: 20 independent butterflies (pipelined) ----
    float p[SEQ];
    #pragma unroll
    for (int t = 0; t < SEQ; ++t) p[t] = h_hist[t] * wfc;  // wfc=0 on lanes>=50
    #pragma unroll
    for (int off = 32; off > 0; off >>= 1) {
        #pragma unroll
        for (int t = 0; t < SEQ; ++t)
            p[t] += __shfl_xor(p[t], off);
    }
    if (lane == 0) {
        #pragma unroll
        for (int t = 0; t < SEQ; ++t) out[t] = p[t] + bfc;
    }
}

extern "C" void kernel_launch(void* const* d_in, const int* in_sizes, int n_in,
                              void* d_out, int out_size, void* d_ws, size_t ws_size,
                              hipStream_t stream) {
    const float* x    = (const float*)d_in[0];
    const float* w_ih = (const float*)d_in[1];
    const float* w_hh = (const float*)d_in[2];
    const float* b_ih = (const float*)d_in[3];
    const float* b_hh = (const float*)d_in[4];
    const float* w_fc = (const float*)d_in[5];
    const float* b_fc = (const float*)d_in[6];
    float* out = (float*)d_out;

    lstm_last_row_kernel<<<1, 64, 0, stream>>>(x, w_ih, w_hh, b_ih, b_hh,
                                               w_fc, b_fc, out);
}

// Round 4
// 16.161 us; speedup vs baseline: 1.6161x; 1.1703x over previous
//
#include <hip/hip_runtime.h>
#include <math.h>

// SEQ=20, BATCH=131072, IN=1, HID=50. Reference slices out[:, -1:, :] on the
// BATCH axis -> output (20 floats) depends only on batch row 131071.
// Single-wave, barrier-free (main loop), in-register LSTM recurrence.
//  - lane j<50 owns hidden unit j; its 4 w_hh rows live in VGPRs as float2
//  - h broadcast via LDS write + ds_read_b128 (same-wave LDS is in-order,
//    same-address read = broadcast; no barrier)
//  - matvec uses HAND-EMITTED v_pk_fma_f32 (inline asm): 104 packed FMA/step
//    instead of 208 scalar -> halves VALU issue time of the dominant phase
//  - fc reduction deferred past the loop: 20 independent butterflies pipeline

typedef float v2f __attribute__((ext_vector_type(2)));

constexpr int SEQ   = 20;
constexpr int BATCH = 131072;
constexpr int HID   = 50;

__device__ __forceinline__ float bcast(float v, int srcLane) {
    return __uint_as_float(__builtin_amdgcn_readlane(__float_as_uint(v), srcLane));
}
__device__ __forceinline__ float rcp_fast(float v) {
    return __builtin_amdgcn_rcpf(v);
}
__device__ __forceinline__ float sigmoid_f(float v) {
    return rcp_fast(1.0f + __expf(-v));     // limits: +inf->0, 0->1 (exact)
}
__device__ __forceinline__ float tanh_f(float v) {
    return 1.0f - 2.0f * rcp_fast(__expf(2.0f * v) + 1.0f);  // NaN-safe both limits
}

// acc.xy = fma(a.xy, b.xy, acc.xy) — register-only VOP3P, no ordering hazard.
#define PKFMA(acc, a, b) \
    asm("v_pk_fma_f32 %0, %1, %2, %0" : "+v"(acc) : "v"(a), "v"(b))

__global__ __launch_bounds__(64, 1)
void lstm_last_row_kernel(const float* __restrict__ x,      // (SEQ, BATCH, 1)
                          const float* __restrict__ w_ih,   // (200, 1)
                          const float* __restrict__ w_hh,   // (200, 50)
                          const float* __restrict__ b_ih,   // (200,)
                          const float* __restrict__ b_hh,   // (200,)
                          const float* __restrict__ w_fc,   // (1, 50)
                          const float* __restrict__ b_fc,   // (1,)
                          float* __restrict__ out)          // (SEQ,1,1) = 20
{
    __shared__ __align__(16) float s_w[4 * HID * HID];  // 40 KB staged w_hh
    __shared__ __align__(16) float s_h[52];             // h + zero pad (13*float4)

    const int lane = threadIdx.x;                       // single wave
    const int j    = (lane < HID) ? lane : (HID - 1);   // clamp idle lanes

    // ---- coalesced stage of w_hh (2500 float4) into LDS ----
    const float4* wsrc = reinterpret_cast<const float4*>(w_hh);
    float4*       wdst = reinterpret_cast<float4*>(s_w);
    #pragma unroll
    for (int i = 0; i < 39; ++i)
        wdst[lane + i * 64] = wsrc[lane + i * 64];
    if (lane < 2500 - 39 * 64)                          // tail: 4 float4
        wdst[lane + 39 * 64] = wsrc[lane + 39 * 64];
    if (lane < 52) s_h[lane] = 0.0f;                    // h0 = 0 (+ zero pad)
    __syncthreads();

    // ---- per-lane weight rows (i,f,g,o for unit j) as v2f pairs ----
    v2f w2[4][26];                                      // pair 25 = 0 (pad)
    #pragma unroll
    for (int g = 0; g < 4; ++g) {
        const float* row = &s_w[(g * HID + j) * HID];   // 8B-aligned (200B rows)
        #pragma unroll
        for (int k = 0; k < 25; ++k)
            w2[g][k] = *reinterpret_cast<const v2f*>(row + 2 * k);
        w2[g][25] = (v2f){0.0f, 0.0f};
    }

    float bias[4], wih[4];
    #pragma unroll
    for (int g = 0; g < 4; ++g) {
        const int r = g * HID + j;
        bias[g] = b_ih[r] + b_hh[r];
        wih[g]  = w_ih[r];                              // IN == 1
    }
    const float wfc = (lane < HID) ? w_fc[lane] : 0.0f;
    const float bfc = b_fc[0];

    // ---- preload all 20 x scalars in parallel ----
    float xv = 0.0f;
    if (lane < SEQ) xv = x[(size_t)lane * BATCH + (BATCH - 1)];

    float h = 0.0f, c = 0.0f;
    float h_hist[SEQ];

    #pragma unroll
    for (int t = 0; t < SEQ; ++t) {
        // publish h_{t-1}; t=0 rewrites the zeros (harmless). Same-wave LDS
        // is processed in order -> no barrier needed.
        if (lane < HID) s_h[lane] = h;

        const float xt = bcast(xv, t);
        v2f a[4][2];                                    // 2 chains/gate for ILP
        #pragma unroll
        for (int g = 0; g < 4; ++g) {
            a[g][0] = (v2f){fmaf(xt, wih[g], bias[g]), 0.0f};
            a[g][1] = (v2f){0.0f, 0.0f};
        }

        #pragma unroll
        for (int i = 0; i < 13; ++i) {
            const float4 hv = *reinterpret_cast<const float4*>(&s_h[i * 4]);
            const v2f hlo = (v2f){hv.x, hv.y};
            const v2f hhi = (v2f){hv.z, hv.w};
            PKFMA(a[0][0], hlo, w2[0][2 * i]);
            PKFMA(a[1][0], hlo, w2[1][2 * i]);
            PKFMA(a[2][0], hlo, w2[2][2 * i]);
            PKFMA(a[3][0], hlo, w2[3][2 * i]);
            PKFMA(a[0][1], hhi, w2[0][2 * i + 1]);
            PKFMA(a[1][1], hhi, w2[1][2 * i + 1]);
            PKFMA(a[2][1], hhi, w2[2][2 * i + 1]);
            PKFMA(a[3][1], hhi, w2[3][2 * i + 1]);
        }

        const float ig = sigmoid_f((a[0][0].x + a[0][0].y) + (a[0][1].x + a[0][1].y));
        const float fg = sigmoid_f((a[1][0].x + a[1][0].y) + (a[1][1].x + a[1][1].y));
        const float gg = tanh_f   ((a[2][0].x + a[2][0].y) + (a[2][1].x + a[2][1].y));
        const float og = sigmoid_f((a[3][0].x + a[3][0].y) + (a[3][1].x + a[3][1].y));
        c = fmaf(fg, c, ig * gg);
        h = og * tanh_f(c);
        h_hist[t] = h;
    }

    // ---- deferred fc epilogue: 20 independent butterflies (pipelined) ----
    float p[SEQ];
    #pragma unroll
    for (int t = 0; t < SEQ; ++t) p[t] = h_hist[t] * wfc;  // wfc=0 on lanes>=50
    #pragma unroll
    for (int off = 32; off > 0; off >>= 1) {
        #pragma unroll
        for (int t = 0; t < SEQ; ++t)
            p[t] += __shfl_xor(p[t], off);
    }
    if (lane == 0) {
        #pragma unroll
        for (int t = 0; t < SEQ; ++t) out[t] = p[t] + bfc;
    }
}

extern "C" void kernel_launch(void* const* d_in, const int* in_sizes, int n_in,
                              void* d_out, int out_size, void* d_ws, size_t ws_size,
                              hipStream_t stream) {
    const float* x    = (const float*)d_in[0];
    const float* w_ih = (const float*)d_in[1];
    const float* w_hh = (const float*)d_in[2];
    const float* b_ih = (const float*)d_in[3];
    const float* b_hh = (const float*)d_in[4];
    const float* w_fc = (const float*)d_in[5];
    const float* b_fc = (const float*)d_in[6];
    float* out = (float*)d_out;

    lstm_last_row_kernel<<<1, 64, 0, stream>>>(x, w_ih, w_hh, b_ih, b_hh,
                                               w_fc, b_fc, out);
}